// Round 16
// baseline (253.043 us; speedup 1.0000x reference)
//
#include <hip/hip_runtime.h>
#include <hip/hip_bf16.h>

constexpr int BN = 8, HH = 512, WW = 512;
constexpr int PIX = HH * WW;
constexpr float EPSF = 1e-4f;

__device__ __forceinline__ float b2f(__hip_bfloat16 x) { return __bfloat162float(x); }
__device__ __forceinline__ __hip_bfloat16 f2b(float x) { return __float2bfloat16(x); }
__device__ __forceinline__ unsigned short bfbits(float x) {
    union { __hip_bfloat16 b; unsigned short u; } cv; cv.b = f2b(x); return cv.u;
}
__device__ __forceinline__ float ubf(unsigned short u) {
    union { unsigned int i; float f; } c; c.i = ((unsigned int)u) << 16; return c.f;
}
// hardware packed f32->bf16 (RNE): D = {hi:cvt(S1), lo:cvt(S0)}
__device__ __forceinline__ unsigned int cvtpk(float lo, float hi) {
    unsigned int r;
    asm("v_cvt_pk_bf16_f32 %0, %1, %2" : "=v"(r) : "v"(lo), "v"(hi));
    return r;
}
// silu via hw rcp (h is bf16-quantized downstream; ~2^-22 rel err invisible)
__device__ __forceinline__ float silu(float a) {
    return a * __builtin_amdgcn_rcpf(1.f + __expf(-a));
}

typedef __attribute__((ext_vector_type(8))) short bf16x8;   // MFMA A/B frag (4 VGPRs)
typedef __attribute__((ext_vector_type(4))) float f32x4;    // MFMA C/D frag

#define MF(acc, A, B) (acc) = __builtin_amdgcn_mfma_f32_16x16x32_bf16((A), (B), (acc), 0, 0, 0)

// load B-frag: 8 consecutive u16 (rows q*8..q*8+7) starting at off16 (must be 4-u16 aligned)
__device__ __forceinline__ bf16x8 ldb(const unsigned short* s, int off16) {
    const uint2* p = (const uint2*)(s + off16);
    uint2 a = p[0], c = p[1];
    union { uint4 u; bf16x8 v; } cv;
    cv.u = make_uint4(a.x, a.y, c.x, c.y);
    return cv.v;
}

// ---- workspace float offsets (no zeroing required anywhere: every slot is
// fully overwritten each launch by plain stores) ----
constexpr int OFF_COR = 640;     // corners [b][hi][wi][16] -> 640..1151
constexpr int OFF_PR0 = 1280;    // row0 partials [b][8 bx][16]
constexpr int OFF_PR1 = 2304;    // row511 partials
constexpr int OFF_PC0 = 3328;    // col0 partials [b][64 by][4 wave][16]
constexpr int OFF_PC1 = 36096;   // col511 partials
constexpr int OFF_PART = 90112;  // conv3 TOT partials [b][512 blocks][16] = 65536 floats
// ---- big buffers: tpl transposed [plane][b][j][h]; t0/t3 bf16, t1/t2 fp32 ----
constexpr size_t OFF_TP0 = 655360;                         // bytes (622,592 used below)
constexpr size_t SZ_TPH = (size_t)BN * PIX * 2;            // 4 MB (u16 plane)
constexpr size_t SZ_TPF = (size_t)BN * PIX * 4;            // 8 MB (f32 plane)
constexpr size_t OFF_TP1 = OFF_TP0 + SZ_TPH;
constexpr size_t OFF_TP2 = OFF_TP1 + SZ_TPF;
constexpr size_t OFF_TP3 = OFF_TP2 + SZ_TPF;
constexpr size_t WS_NEEDED = OFF_TP3 + SZ_TPH;             // ~25.8 MB

// ---------------- fused conv1(MFMA)+conv2(MFMA)+RGB with conv3-mean reduction ----------------
// (round-15 version, frozen -- CONTROL)
__global__ __launch_bounds__(256) void conv12_kernel(const float* __restrict__ batch,
                                                     const float* __restrict__ w1,
                                                     const float* __restrict__ b1,
                                                     const float* __restrict__ w2,
                                                     const float* __restrict__ b2v,
                                                     float* __restrict__ wsf,
                                                     float* __restrict__ out) {
    __shared__ unsigned short stb[3][12][68];
    __shared__ uint4 h1s[10 * 66 * 2];
    __shared__ float part[4][16];

    int tx = threadIdx.x;
    int lane = tx & 63, wave = tx >> 6;
    int n = lane & 15, q = lane >> 4;
    int w0 = blockIdx.x * 64, h0 = blockIdx.y * 8, b = blockIdx.z;

    union { uint4 u; bf16x8 v; } cv;
    const float* pb = batch + (size_t)(b * 3) * PIX;

    unsigned int* stw = (unsigned int*)&stb[0][0][0];
    for (int i = tx; i < 1224; i += 256) {
        int ch = i / 408, rem = i - ch * 408;
        int r = rem / 34, c2 = rem - r * 34;
        int gh = h0 - 2 + r, gw = w0 - 2 + 2 * c2;
        const float* p = pb + (size_t)ch * PIX + (size_t)gh * WW;
        bool rok = (gh >= 0) && (gh < HH);
        float v0 = (rok && gw >= 0 && gw < WW) ? p[gw] : 0.f;
        float v1 = (rok && gw + 1 >= 0 && gw + 1 < WW) ? p[gw + 1] : 0.f;
        stw[i] = cvtpk(v0, v1);
    }

    // ---- conv1 weight fragments from global: A[oc][k], k=q*8+j ----
    bf16x8 w1h, w1l;
    {
        int oc = lane & 15;
        union { unsigned int w[4]; bf16x8 v; } fh, fl;
#pragma unroll
        for (int jp = 0; jp < 4; jp++) {
            int k0 = q * 8 + 2 * jp, k1 = k0 + 1;
            float v0 = (k0 < 27) ? w1[oc * 27 + k0] : 0.f;
            float v1 = (k1 < 27) ? w1[oc * 27 + k1] : 0.f;
            unsigned int hi = cvtpk(v0, v1);
            float h0f = ubf((unsigned short)(hi & 0xFFFFu));
            float h1f = ubf((unsigned short)(hi >> 16));
            fh.w[jp] = hi;
            fl.w[jp] = cvtpk(v0 - h0f, v1 - h1f);
        }
        w1h = fh.v; w1l = fl.v;
    }
    int koff[8];
#pragma unroll
    for (int j = 0; j < 8; j++) {
        int k = q * 8 + j;
        int kk = (k < 27) ? k : 0;
        int ic = kk / 9, rem = kk - ic * 9, kh = rem / 3, kw = rem - kh * 3;
        koff[j] = ic * 816 + kh * 68 + kw;
    }
    float b1q[4];
#pragma unroll
    for (int r = 0; r < 4; r++) b1q[r] = b1[q * 4 + r];
    bool hiq = (q == 3);
    __syncthreads();

    const unsigned short* sptr = &stb[0][0][0];
    unsigned int* hw = (unsigned int*)h1s;
    union U8 { unsigned short h[8]; unsigned int w[4]; bf16x8 v; };
    int i_c = wave * 16 + n;                          // first pixel (always < 660)
    int r_c = (unsigned)i_c / 66u; int c_c = i_c - r_c * 66;
    int base_c = r_c * 68 + c_c;
    U8 curv;
#pragma unroll
    for (int j = 0; j < 8; j++) curv.h[j] = sptr[base_c + koff[j]];
    for (int gi = 0; gi < 11; gi++) {
        U8 nxtv;
        int i_n = 0, r_n = 0, c_n = 0, base_n = 0;
        if (gi < 10) {
            i_n = i_c + 64;
            int wrap = (c_c >= 2);
            c_n = wrap ? (c_c - 2) : (c_c + 64);
            r_n = r_c + wrap;
            base_n = base_c + (wrap ? 66 : 64);
            if (i_n > 659) { i_n = 659; r_n = 9; c_n = 65; base_n = 677; }
#pragma unroll
            for (int j = 0; j < 8; j++) nxtv.h[j] = sptr[base_n + koff[j]];
        } else {
#pragma unroll
            for (int j = 0; j < 4; j++) nxtv.w[j] = 0u;
        }
        if (hiq) {                                    // q==3: k=27..31 padded -> zero
            curv.w[1] &= 0xFFFFu; curv.w[2] = 0u; curv.w[3] = 0u;
        }
        f32x4 a = {0, 0, 0, 0};
        MF(a, w1h, curv.v);
        MF(a, w1l, curv.v);
        int gh = h0 - 1 + r_c, gw = w0 - 1 + c_c;
        bool ok = ((unsigned)gh < (unsigned)HH) && ((unsigned)gw < (unsigned)WW);
        unsigned int p0 = cvtpk(silu(a[0] + b1q[0]), silu(a[1] + b1q[1]));
        unsigned int p1 = cvtpk(silu(a[2] + b1q[2]), silu(a[3] + b1q[3]));
        p0 = ok ? p0 : 0u;                            // conv2 zero padding
        p1 = ok ? p1 : 0u;
        int swz = (c_c >> 2) & 1;
        int slot = i_c * 2 + ((q >= 2) ? (swz ^ 1) : swz);
        *(uint2*)&hw[slot * 4 + (q & 1) * 2] = make_uint2(p0, p1);
        curv = nxtv;
        i_c = i_n; r_c = r_n; c_c = c_n; base_c = base_n;
    }

    for (int j = tx; j < 512; j += 256) {
        int rr = j >> 6, ccx = j & 63;
        size_t p = (size_t)(h0 + rr) * WW + (w0 + ccx);
        float v0 = pb[p], v1 = pb[(size_t)PIX + p], v2 = pb[2 * (size_t)PIX + p];
        int mx  = (v0 >= v1 && v0 >= v2) ? 0 : ((v1 >= v2) ? 1 : 2);
        int mx2 = (v2 >= v1 && v2 >= v0) ? 2 : ((v1 >= v0) ? 1 : 0);
        int mn  = (v0 <= v1 && v0 <= v2) ? 0 : ((v1 <= v2) ? 1 : 2);
        int mn2 = (v2 <= v1 && v2 <= v0) ? 2 : ((v1 <= v0) ? 1 : 0);
#pragma unroll
        for (int c = 0; c < 3; c++) {
            float r = 0.5f * ((float)(c == mx) + (float)(c == mx2))
                    - 0.5f * ((float)(c == mn) + (float)(c == mn2));
            out[(size_t)(b * 6 + 2 + c) * PIX + p] = r;
        }
    }
    __syncthreads();

    // ---- conv2 weight fragments from global ----
    bf16x8 ah[5], al[5];
    {
        int oc = lane & 15;
#pragma unroll
        for (int ks = 0; ks < 5; ks++) {
            union { unsigned int w[4]; bf16x8 v; } fh, fl;
#pragma unroll
            for (int jp = 0; jp < 4; jp++) {
                int k0 = q * 8 + 2 * jp, k1 = k0 + 1;
                int tap0 = 2 * ks + (k0 >> 4), ic0 = k0 & 15;
                int tap1 = 2 * ks + (k1 >> 4), ic1 = k1 & 15;
                float v0 = (tap0 <= 8) ? w2[oc * 144 + ic0 * 9 + tap0] : 0.f;
                float v1 = (tap1 <= 8) ? w2[oc * 144 + ic1 * 9 + tap1] : 0.f;
                unsigned int hi = cvtpk(v0, v1);
                float h0f = ubf((unsigned short)(hi & 0xFFFFu));
                float h1f = ubf((unsigned short)(hi >> 16));
                fh.w[jp] = hi;
                fl.w[jp] = cvtpk(v0 - h0f, v1 - h1f);
            }
            ah[ks] = fh.v; al[ks] = fl.v;
        }
    }
    float b2q[4];
#pragma unroll
    for (int r = 0; r < 4; r++) b2q[r] = b2v[q * 4 + r];
    int halfb = q & 1;

    float tt[4] = {0, 0, 0, 0};
    float cs0[4] = {0, 0, 0, 0};
    float cs1[4] = {0, 0, 0, 0};
    for (int rloc = 0; rloc < 2; rloc++) {
        int row = wave * 2 + rloc;
        int grow = h0 + row;
        f32x4 acc[4] = {{0,0,0,0},{0,0,0,0},{0,0,0,0},{0,0,0,0}};
#pragma unroll
        for (int ks = 0; ks < 5; ks++) {
            int tap = 2 * ks + (q >> 1); if (tap > 8) tap = 8;
            int dh = tap / 3 - 1, dw = tap % 3 - 1;
            int lr = row + 1 + dh;
            int c0 = 1 + dw + n;                      // bit2 of c is t-invariant (c=c0+16t)
            const uint4* pp = &h1s[(lr * 66 + c0) * 2 + (halfb ^ ((c0 >> 2) & 1))];
            bf16x8 B[4];
#pragma unroll
            for (int t = 0; t < 4; t++) { cv.u = pp[t * 32]; B[t] = cv.v; }
#pragma unroll
            for (int t = 0; t < 4; t++) { MF(acc[t], ah[ks], B[t]); MF(acc[t], al[ks], B[t]); }
        }
        float sv[4][4];
#pragma unroll
        for (int t = 0; t < 4; t++)
#pragma unroll
            for (int r = 0; r < 4; r++)
                sv[t][r] = silu(acc[t][r] + b2q[r]);
#pragma unroll
        for (int r = 0; r < 4; r++) tt[r] += sv[0][r] + sv[1][r] + sv[2][r] + sv[3][r];
        if (grow == 0 || grow == HH - 1) {
            int off = (grow == 0) ? OFF_PR0 : OFF_PR1;
#pragma unroll
            for (int r = 0; r < 4; r++) {
                float x = sv[0][r] + sv[1][r] + sv[2][r] + sv[3][r];
#pragma unroll
                for (int d = 1; d < 16; d <<= 1) x += __shfl_xor(x, d, 64);
                if (n == 0) wsf[off + (b * 8 + (int)blockIdx.x) * 16 + q * 4 + r] = x;
            }
        }
        if (blockIdx.x == 0 && n == 0)
#pragma unroll
            for (int r = 0; r < 4; r++) cs0[r] += sv[0][r];
        if (blockIdx.x == 7 && n == 15)
#pragma unroll
            for (int r = 0; r < 4; r++) cs1[r] += sv[3][r];
        if ((grow == 0 || grow == HH - 1)) {
            int hi = (grow == 0) ? 0 : 1;
            if (blockIdx.x == 0 && n == 0)
#pragma unroll
                for (int r = 0; r < 4; r++)
                    wsf[OFF_COR + ((b * 2 + hi) * 2 + 0) * 16 + q * 4 + r] = sv[0][r];
            if (blockIdx.x == 7 && n == 15)
#pragma unroll
                for (int r = 0; r < 4; r++)
                    wsf[OFF_COR + ((b * 2 + hi) * 2 + 1) * 16 + q * 4 + r] = sv[3][r];
        }
    }
    if (blockIdx.x == 0 && n == 0)
#pragma unroll
        for (int r = 0; r < 4; r++)
            wsf[OFF_PC0 + (((size_t)b * 64 + blockIdx.y) * 4 + wave) * 16 + q * 4 + r] = cs0[r];
    if (blockIdx.x == 7 && n == 15)
#pragma unroll
        for (int r = 0; r < 4; r++)
            wsf[OFF_PC1 + (((size_t)b * 64 + blockIdx.y) * 4 + wave) * 16 + q * 4 + r] = cs1[r];
#pragma unroll
    for (int r = 0; r < 4; r++) {
        float x = tt[r];
#pragma unroll
        for (int d = 1; d < 16; d <<= 1) x += __shfl_xor(x, d, 64);
        tt[r] = x;
    }
    if (n == 0)
#pragma unroll
        for (int r = 0; r < 4; r++) part[wave][q * 4 + r] = tt[r];
    __syncthreads();
    if (tx < 16) {
        int blk = blockIdx.y * 8 + blockIdx.x;        // 0..511
        wsf[OFF_PART + ((size_t)b * 512 + blk) * 16 + tx] =
            part[0][tx] + part[1][tx] + part[2][tx] + part[3][tx];
    }
}

// ---------------- inline filter: slot partials -> normalized taps sEn/sCn (LDS) ----------------
// Identical summation order and RNE ops to the old filter_kernel -> bit-identical taps
// in every block. scr: >=344 floats. Ends with __syncthreads (sEn/sCn valid after).
__device__ __forceinline__ void taps_inline(const float* __restrict__ wsf,
                                            const float* __restrict__ w3,
                                            const float* __restrict__ b3,
                                            int b, int t,
                                            float* sEn, float* sCn, float* scr) {
    // TOT from 512 per-block partials
    if (t < 128) {
        int ic = t & 15, ch = t >> 4;
        const float* pp = wsf + OFF_PART + ((size_t)b * 512 + ch * 64) * 16 + ic;
        float s = 0.f;
        for (int k = 0; k < 64; k++) s += pp[k * 16];
        scr[t] = s;
    }
    __syncthreads();
    if (t < 16) {                          // stot
        float a = 0.f;
        for (int c2 = 0; c2 < 8; c2++) a += scr[c2 * 16 + t];
        scr[160 + t] = a;
    } else if (t < 32) {                   // row0
        int ic = t - 16; float s = 0.f;
        for (int i = 0; i < 8; i++) s += wsf[OFF_PR0 + (b * 8 + i) * 16 + ic];
        scr[176 + ic] = s;
    } else if (t < 48) {                   // row511
        int ic = t - 32; float s = 0.f;
        for (int i = 0; i < 8; i++) s += wsf[OFF_PR1 + (b * 8 + i) * 16 + ic];
        scr[192 + ic] = s;
    }
    __syncthreads();
    if (t < 128) {                         // col0 partials (64 by x 4 wave = 256 slots)
        int ic = t & 15, ch = t >> 4;
        const float* pp = wsf + OFF_PC0 + ((size_t)b * 256 + ch * 32) * 16 + ic;
        float s = 0.f;
        for (int k = 0; k < 32; k++) s += pp[k * 16];
        scr[t] = s;
    }
    __syncthreads();
    if (t < 16) {
        float a = 0.f;
        for (int c2 = 0; c2 < 8; c2++) a += scr[c2 * 16 + t];
        scr[208 + t] = a;
    }
    __syncthreads();
    if (t < 128) {                         // col511 partials
        int ic = t & 15, ch = t >> 4;
        const float* pp = wsf + OFF_PC1 + ((size_t)b * 256 + ch * 32) * 16 + ic;
        float s = 0.f;
        for (int k = 0; k < 32; k++) s += pp[k * 16];
        scr[t] = s;
    }
    __syncthreads();
    if (t < 16) {
        float a = 0.f;
        for (int c2 = 0; c2 < 8; c2++) a += scr[c2 * 16 + t];
        scr[224 + t] = a;
    }
    __syncthreads();
    // red: w3-weighted tap totals via edge algebra
    if (t < 144) {
        int ic = t / 9, tap = t % 9, kh = tap / 3, kw = tap % 3;
        float T = scr[160 + ic];
        int hi = -1, wi = -1;
        if (kh == 0) { T -= scr[192 + ic]; hi = 1; }
        else if (kh == 2) { T -= scr[176 + ic]; hi = 0; }
        if (kw == 0) { T -= scr[224 + ic]; wi = 1; }
        else if (kw == 2) { T -= scr[208 + ic]; wi = 0; }
        if (hi >= 0 && wi >= 0) T += wsf[OFF_COR + ((b * 2 + hi) * 2 + wi) * 16 + ic];
        scr[t] = w3[t] * T;
    }
    __syncthreads();
    if (t == 0) {
        float S = 0.f;
        for (int i = 0; i < 144; i++) S += scr[i];
        scr[240] = b3[0] + S * (1.f / (float)PIX);   // mean
    }
    __syncthreads();
    float scale = fminf(2.5f, fmaxf(-2.5f, scr[240]));
    float sd = exp2f(scale);
    float fs = ceilf(3.f * sd + 0.5f);
    float e = 0.f, c = 0.f;
    if (t < 37) {
        float x = (float)(t - 18);
        if (fabsf(x) <= fs) {
            float qq = x / sd;
            e = __expf(-0.5f * qq * qq);
            c = -x / (sd * sd * sd * 6.28318530717958647692f) * e;
        }
        scr[256 + t] = e;
        scr[300 + t] = fabsf(c);
    }
    __syncthreads();
    if (t == 0) {
        float a = 0.f, d2 = 0.f;
        for (int i = 0; i < 37; i++) { a += scr[256 + i]; d2 += scr[300 + i]; }
        scr[241] = a; scr[242] = d2;
    }
    __syncthreads();
    if (t < 37) {
        sEn[t] = e / scr[241];
        sCn[t] = c / scr[242];
    }
    __syncthreads();
}

// per-lane band A-fragments from LDS taps (same RNE splits as the old filter AFR build)
__device__ __forceinline__ void build_frags(const float* sEn, const float* sCn, int lane,
                                            bf16x8 (&Ae)[2][3], bf16x8 (&Ac)[2][2]) {
    int r = lane & 15, qq = lane >> 4;
#define PK2(a0, a1) ((unsigned)(a0) | ((unsigned)(a1) << 16))
#pragma unroll
    for (int ks = 0; ks < 2; ks++) {
        union { unsigned int w[4]; bf16x8 v; } feh, fem, fel, fch, fcm;
#pragma unroll
        for (int jp = 0; jp < 4; jp++) {
            unsigned short eh2[2], em2[2], el2[2], ch2[2], cm2[2];
#pragma unroll
            for (int s = 0; s < 2; s++) {
                int j2 = 2 * jp + s;
                int d = ks * 32 + qq * 8 + j2 - r;
                bool ok = (d >= 0) && (d <= 36);
                float ve = ok ? sEn[ok ? d : 0] : 0.f;
                float vc = ok ? sCn[ok ? d : 0] : 0.f;
                eh2[s] = bfbits(ve);
                float r1 = ve - ubf(eh2[s]);
                em2[s] = bfbits(r1);
                el2[s] = bfbits(r1 - ubf(em2[s]));
                ch2[s] = bfbits(vc);
                cm2[s] = bfbits(vc - ubf(ch2[s]));
            }
            feh.w[jp] = PK2(eh2[0], eh2[1]);
            fem.w[jp] = PK2(em2[0], em2[1]);
            fel.w[jp] = PK2(el2[0], el2[1]);
            fch.w[jp] = PK2(ch2[0], ch2[1]);
            fcm.w[jp] = PK2(cm2[0], cm2[1]);
        }
        Ae[ks][0] = feh.v; Ae[ks][1] = fem.v; Ae[ks][2] = fel.v;
        Ac[ks][0] = fch.v; Ac[ks][1] = fcm.v;
    }
#undef PK2
}

// ---------------- horizontal pass (MFMA) + inline filter: batch -> xg -> t0..t3 ----------------
__global__ __launch_bounds__(256) void horiz_kernel(const float* __restrict__ batch,
                                                    const float* __restrict__ gcm,
                                                    const float* __restrict__ w3,
                                                    const float* __restrict__ b3,
                                                    const float* __restrict__ wsf,
                                                    unsigned short* __restrict__ tp0,
                                                    float* __restrict__ tp1,
                                                    float* __restrict__ tp2,
                                                    unsigned short* __restrict__ tp3) {
    __shared__ unsigned short sx[7 * 32 * 84];   // 37,632 B
    __shared__ float sEn[37], sCn[37], scr[344];
    int tx = threadIdx.x;
    int lane = tx & 63, wave = tx >> 6;
    int n = lane & 15, q = lane >> 4;
    int j0 = blockIdx.x * 32, h0 = blockIdx.y * 32, b = blockIdx.z;
    const float* pb = batch + (size_t)(b * 3) * PIX;
    float g0 = gcm[0], g1 = gcm[1], g2 = gcm[2];
    float g3 = gcm[3], g4 = gcm[4], g5 = gcm[5];
    float g6 = gcm[6], g7 = gcm[7], g8 = gcm[8];
    for (int it = 0; it < 3; it++) {
        int qi = tx + it * 256;
        if (qi < 640) {
            int hh = qi / 20, qc = qi - hh * 20;
            int sc0 = qc * 4;
            int gc0 = j0 - 18 + sc0;
            const float* prow = pb + (size_t)(h0 + hh) * WW;
            float v0[4], v1[4], v2[4];
            if (gc0 >= 0 && gc0 + 3 < WW) {
                float2 a0 = *(const float2*)(prow + gc0);
                float2 a1 = *(const float2*)(prow + gc0 + 2);
                float2 b0 = *(const float2*)(prow + PIX + gc0);
                float2 b1 = *(const float2*)(prow + PIX + gc0 + 2);
                float2 c0 = *(const float2*)(prow + 2 * (size_t)PIX + gc0);
                float2 c1 = *(const float2*)(prow + 2 * (size_t)PIX + gc0 + 2);
                v0[0] = a0.x; v0[1] = a0.y; v0[2] = a1.x; v0[3] = a1.y;
                v1[0] = b0.x; v1[1] = b0.y; v1[2] = b1.x; v1[3] = b1.y;
                v2[0] = c0.x; v2[1] = c0.y; v2[2] = c1.x; v2[3] = c1.y;
            } else {
#pragma unroll
                for (int e = 0; e < 4; e++) {
                    int gc = gc0 + e;
                    bool okc = (unsigned)gc < (unsigned)WW;
                    v0[e] = okc ? prow[gc] : 0.f;
                    v1[e] = okc ? prow[(size_t)PIX + gc] : 0.f;
                    v2[e] = okc ? prow[2 * (size_t)PIX + gc] : 0.f;
                }
            }
            unsigned short x0b[4], h1b[4], m1b[4], l1b[4], h2b[4], m2b[4], l2b[4];
#pragma unroll
            for (int e = 0; e < 4; e++) {
                float x0 = g0 * v0[e] + g1 * v1[e] + g2 * v2[e];
                float x1 = g3 * v0[e] + g4 * v1[e] + g5 * v2[e];
                float x2 = g6 * v0[e] + g7 * v1[e] + g8 * v2[e];
                x0b[e] = bfbits(x0);
                h1b[e] = bfbits(x1); float r1 = x1 - ubf(h1b[e]);
                m1b[e] = bfbits(r1); l1b[e] = bfbits(r1 - ubf(m1b[e]));
                h2b[e] = bfbits(x2); float r2 = x2 - ubf(h2b[e]);
                m2b[e] = bfbits(r2); l2b[e] = bfbits(r2 - ubf(m2b[e]));
            }
            int o = hh * 84 + sc0;
            *(ushort4*)&sx[o]            = make_ushort4(x0b[0], x0b[1], x0b[2], x0b[3]);
            *(ushort4*)&sx[2688 + o]     = make_ushort4(h1b[0], h1b[1], h1b[2], h1b[3]);
            *(ushort4*)&sx[2 * 2688 + o] = make_ushort4(m1b[0], m1b[1], m1b[2], m1b[3]);
            *(ushort4*)&sx[3 * 2688 + o] = make_ushort4(l1b[0], l1b[1], l1b[2], l1b[3]);
            *(ushort4*)&sx[4 * 2688 + o] = make_ushort4(h2b[0], h2b[1], h2b[2], h2b[3]);
            *(ushort4*)&sx[5 * 2688 + o] = make_ushort4(m2b[0], m2b[1], m2b[2], m2b[3]);
            *(ushort4*)&sx[6 * 2688 + o] = make_ushort4(l2b[0], l2b[1], l2b[2], l2b[3]);
        }
    }
    // inline filter (syncs inside also cover the staging writes above)
    taps_inline(wsf, w3, b3, b, tx, sEn, sCn, scr);
    bf16x8 Ae[2][3], Ac[2][2];
    build_frags(sEn, sCn, lane, Ae, Ac);
    int jt = wave & 1, ht = wave >> 1;
    f32x4 a0 = {0,0,0,0}, a1 = {0,0,0,0}, a2 = {0,0,0,0}, a3 = {0,0,0,0};
    int rb = (ht * 16 + n) * 84 + jt * 16 + q * 8;
#pragma unroll
    for (int ks = 0; ks < 2; ks++) {
        int rk = rb + ks * 32;
        bf16x8 B0  = ldb(sx, rk);
        bf16x8 B1h = ldb(sx, 2688 + rk), B1m = ldb(sx, 2 * 2688 + rk), B1l = ldb(sx, 3 * 2688 + rk);
        bf16x8 B2h = ldb(sx, 4 * 2688 + rk), B2m = ldb(sx, 5 * 2688 + rk), B2l = ldb(sx, 6 * 2688 + rk);
        MF(a0, Ae[ks][0], B0); MF(a0, Ae[ks][1], B0);
        MF(a3, Ac[ks][0], B0); MF(a3, Ac[ks][1], B0);
        MF(a1, Ae[ks][0], B1h); MF(a1, Ae[ks][0], B1m); MF(a1, Ae[ks][1], B1h);
        MF(a1, Ae[ks][0], B1l); MF(a1, Ae[ks][2], B1h); MF(a1, Ae[ks][1], B1m);
        MF(a2, Ae[ks][0], B2h); MF(a2, Ae[ks][0], B2m); MF(a2, Ae[ks][1], B2h);
        MF(a2, Ae[ks][0], B2l); MF(a2, Ae[ks][2], B2h); MF(a2, Ae[ks][1], B2m);
    }
    int jo = j0 + jt * 16 + q * 4;
    int ho = h0 + ht * 16 + n;
#pragma unroll
    for (int r = 0; r < 4; r++) {
        size_t ix = ((size_t)b * 512 + (jo + r)) * 512 + ho;
        tp0[ix] = bfbits(a0[r]);
        tp1[ix] = a1[r];
        tp2[ix] = a2[r];
        tp3[ix] = bfbits(a3[r]);
    }
}

// ---------------- vertical pass (MFMA) + inline filter + final math -> out ch0,1,5 ----------------
__global__ __launch_bounds__(256) void vert_kernel(const float* __restrict__ wsf,
                                                   const float* __restrict__ w3,
                                                   const float* __restrict__ b3,
                                                   const unsigned short* __restrict__ tp0,
                                                   const float* __restrict__ tp1,
                                                   const float* __restrict__ tp2,
                                                   const unsigned short* __restrict__ tp3,
                                                   float* __restrict__ out) {
    __shared__ unsigned short sb[8 * 32 * 84];   // 43,008 B
    __shared__ float sEn[37], sCn[37], scr[344];
    int tx = threadIdx.x;
    int lane = tx & 63, wave = tx >> 6;
    int n = lane & 15, q = lane >> 4;
    int j0 = blockIdx.x * 32, r0 = blockIdx.y * 32, b = blockIdx.z;
    for (int it = 0; it < 3; it++) {
        int qi = tx + it * 256;
        if (qi < 640) {
            int jj = qi / 20, qc = qi - jj * 20;
            int sr0 = qc * 4;
            int gh0 = r0 - 18 + sr0;
            size_t ixb = ((size_t)b * 512 + (j0 + jj)) * 512;
            unsigned int t0a, t0b, t3a, t3b;
            float f1[4], f2[4];
            if (gh0 >= 0 && gh0 + 3 < HH) {
                size_t ix0 = ixb + gh0;
                t0a = *(const unsigned int*)&tp0[ix0];
                t0b = *(const unsigned int*)&tp0[ix0 + 2];
                t3a = *(const unsigned int*)&tp3[ix0];
                t3b = *(const unsigned int*)&tp3[ix0 + 2];
                float2 fa = *(const float2*)&tp1[ix0];
                float2 fb = *(const float2*)&tp1[ix0 + 2];
                float2 fc = *(const float2*)&tp2[ix0];
                float2 fd = *(const float2*)&tp2[ix0 + 2];
                f1[0] = fa.x; f1[1] = fa.y; f1[2] = fb.x; f1[3] = fb.y;
                f2[0] = fc.x; f2[1] = fc.y; f2[2] = fd.x; f2[3] = fd.y;
            } else {
                unsigned short u0[4] = {0, 0, 0, 0}, u3[4] = {0, 0, 0, 0};
#pragma unroll
                for (int e = 0; e < 4; e++) {
                    f1[e] = 0.f; f2[e] = 0.f;
                    int gh = gh0 + e;
                    if ((unsigned)gh < (unsigned)HH) {
                        size_t ix = ixb + gh;
                        u0[e] = tp0[ix]; f1[e] = tp1[ix]; f2[e] = tp2[ix]; u3[e] = tp3[ix];
                    }
                }
                t0a = (unsigned)u0[0] | ((unsigned)u0[1] << 16);
                t0b = (unsigned)u0[2] | ((unsigned)u0[3] << 16);
                t3a = (unsigned)u3[0] | ((unsigned)u3[1] << 16);
                t3b = (unsigned)u3[2] | ((unsigned)u3[3] << 16);
            }
            unsigned short h1b[4], m1b[4], l1b[4], h2b[4], m2b[4], l2b[4];
#pragma unroll
            for (int e = 0; e < 4; e++) {
                h1b[e] = bfbits(f1[e]); float r1 = f1[e] - ubf(h1b[e]);
                m1b[e] = bfbits(r1); l1b[e] = bfbits(r1 - ubf(m1b[e]));
                h2b[e] = bfbits(f2[e]); float r2 = f2[e] - ubf(h2b[e]);
                m2b[e] = bfbits(r2); l2b[e] = bfbits(r2 - ubf(m2b[e]));
            }
            int o = jj * 84 + sr0;
            *(uint2*)&sb[o] = make_uint2(t0a, t0b);
            *(ushort4*)&sb[2688 + o]     = make_ushort4(h1b[0], h1b[1], h1b[2], h1b[3]);
            *(ushort4*)&sb[2 * 2688 + o] = make_ushort4(m1b[0], m1b[1], m1b[2], m1b[3]);
            *(ushort4*)&sb[3 * 2688 + o] = make_ushort4(l1b[0], l1b[1], l1b[2], l1b[3]);
            *(ushort4*)&sb[4 * 2688 + o] = make_ushort4(h2b[0], h2b[1], h2b[2], h2b[3]);
            *(ushort4*)&sb[5 * 2688 + o] = make_ushort4(m2b[0], m2b[1], m2b[2], m2b[3]);
            *(ushort4*)&sb[6 * 2688 + o] = make_ushort4(l2b[0], l2b[1], l2b[2], l2b[3]);
            *(uint2*)&sb[7 * 2688 + o] = make_uint2(t3a, t3b);
        }
    }
    taps_inline(wsf, w3, b3, b, tx, sEn, sCn, scr);
    bf16x8 Ae[2][3], Ac[2][2];
    build_frags(sEn, sCn, lane, Ae, Ac);
    int ct = wave & 1, rt = wave >> 1;
    f32x4 aE = {0,0,0,0}, aX = {0,0,0,0}, aY = {0,0,0,0}, aL = {0,0,0,0}, aLL = {0,0,0,0};
    int rb = (ct * 16 + n) * 84 + rt * 16 + q * 8;
#pragma unroll
    for (int ks = 0; ks < 2; ks++) {
        int rk = rb + ks * 32;
        bf16x8 B0  = ldb(sb, rk);
        bf16x8 B1h = ldb(sb, 2688 + rk), B1m = ldb(sb, 2 * 2688 + rk), B1l = ldb(sb, 3 * 2688 + rk);
        bf16x8 B2h = ldb(sb, 4 * 2688 + rk), B2m = ldb(sb, 5 * 2688 + rk), B2l = ldb(sb, 6 * 2688 + rk);
        bf16x8 B3  = ldb(sb, 7 * 2688 + rk);
        MF(aE, Ae[ks][0], B0); MF(aE, Ae[ks][1], B0);
        MF(aX, Ac[ks][0], B0); MF(aX, Ac[ks][1], B0);
        MF(aY, Ae[ks][0], B3); MF(aY, Ae[ks][1], B3);
        MF(aL, Ae[ks][0], B1h); MF(aL, Ae[ks][0], B1m); MF(aL, Ae[ks][1], B1h);
        MF(aL, Ae[ks][0], B1l); MF(aL, Ae[ks][2], B1h); MF(aL, Ae[ks][1], B1m);
        MF(aLL, Ae[ks][0], B2h); MF(aLL, Ae[ks][0], B2m); MF(aLL, Ae[ks][1], B2h);
        MF(aLL, Ae[ks][0], B2l); MF(aLL, Ae[ks][2], B2h); MF(aLL, Ae[ks][1], B2m);
    }
    int ho = r0 + rt * 16 + q * 4;
    int jo = j0 + ct * 16 + n;
#pragma unroll
    for (int r = 0; r < 4; r++) {
        float E = aE[r], Ex = aX[r], Ey = aY[r], El = aL[r], Ell = aLL[r];
        float Hf = atanf(El / (Ell + EPSF));
        float S = logf((El * El + Ell * Ell) / (E * E + EPSF) + EPSF);
        float rx = Ex / (E + EPSF), ry = Ey / (E + EPSF);
        float Wv = atanf(rx * rx + ry * ry);
        size_t base = (size_t)(b * 6) * PIX + (size_t)(ho + r) * WW + jo;
        out[base] = Hf;
        out[base + PIX] = S;
        out[base + 5 * (size_t)PIX] = Wv;
    }
}

extern "C" void kernel_launch(void* const* d_in, const int* in_sizes, int n_in,
                              void* d_out, int out_size, void* d_ws, size_t ws_size,
                              hipStream_t stream) {
    const float* batch = (const float*)d_in[0];
    const float* gcm   = (const float*)d_in[1];
    const float* w1    = (const float*)d_in[2];
    const float* b1    = (const float*)d_in[3];
    const float* w2    = (const float*)d_in[4];
    const float* b2    = (const float*)d_in[5];
    const float* w3    = (const float*)d_in[6];
    const float* b3    = (const float*)d_in[7];
    float* out = (float*)d_out;

    if (ws_size < WS_NEEDED) return;

    float* wsf = (float*)d_ws;
    unsigned short* tp0 = (unsigned short*)((char*)d_ws + OFF_TP0);
    float* tp1 = (float*)((char*)d_ws + OFF_TP1);
    float* tp2 = (float*)((char*)d_ws + OFF_TP2);
    unsigned short* tp3 = (unsigned short*)((char*)d_ws + OFF_TP3);

    conv12_kernel<<<dim3(8, 64, 8), dim3(256), 0, stream>>>(
        batch, w1, b1, w2, b2, wsf, out);
    horiz_kernel<<<dim3(16, 16, 8), dim3(256), 0, stream>>>(
        batch, gcm, w3, b3, wsf, tp0, tp1, tp2, tp3);
    vert_kernel<<<dim3(16, 16, 8), dim3(256), 0, stream>>>(
        wsf, w3, b3, tp0, tp1, tp2, tp3, out);
}

// Round 17
// 224.025 us; speedup vs baseline: 1.1295x; 1.1295x over previous
//
#include <hip/hip_runtime.h>
#include <hip/hip_bf16.h>

constexpr int BN = 8, HH = 512, WW = 512;
constexpr int PIX = HH * WW;
constexpr float EPSF = 1e-4f;

__device__ __forceinline__ float b2f(__hip_bfloat16 x) { return __bfloat162float(x); }
__device__ __forceinline__ __hip_bfloat16 f2b(float x) { return __float2bfloat16(x); }
__device__ __forceinline__ unsigned short bfbits(float x) {
    union { __hip_bfloat16 b; unsigned short u; } cv; cv.b = f2b(x); return cv.u;
}
__device__ __forceinline__ float ubf(unsigned short u) {
    union { unsigned int i; float f; } c; c.i = ((unsigned int)u) << 16; return c.f;
}
// hardware packed f32->bf16 (RNE): D = {hi:cvt(S1), lo:cvt(S0)}
__device__ __forceinline__ unsigned int cvtpk(float lo, float hi) {
    unsigned int r;
    asm("v_cvt_pk_bf16_f32 %0, %1, %2" : "=v"(r) : "v"(lo), "v"(hi));
    return r;
}
// silu via hw rcp (h is bf16-quantized downstream; ~2^-22 rel err invisible)
__device__ __forceinline__ float silu(float a) {
    return a * __builtin_amdgcn_rcpf(1.f + __expf(-a));
}

typedef __attribute__((ext_vector_type(8))) short bf16x8;   // MFMA A/B frag (4 VGPRs)
typedef __attribute__((ext_vector_type(4))) float f32x4;    // MFMA C/D frag

#define MF(acc, A, B) (acc) = __builtin_amdgcn_mfma_f32_16x16x32_bf16((A), (B), (acc), 0, 0, 0)

// load B-frag: 8 consecutive u16 (rows q*8..q*8+7) starting at off16 (must be 4-u16 aligned)
__device__ __forceinline__ bf16x8 ldb(const unsigned short* s, int off16) {
    const uint2* p = (const uint2*)(s + off16);
    uint2 a = p[0], c = p[1];
    union { uint4 u; bf16x8 v; } cv;
    cv.u = make_uint4(a.x, a.y, c.x, c.y);
    return cv.v;
}

// ---- workspace float offsets (small region) ----
constexpr int OFF_TOT = 0;       // 8*16 per-image channel totals (atomics)
constexpr int OFF_ROW0 = 128;
constexpr int OFF_ROW1 = 256;
constexpr int OFF_COL0 = 384;
constexpr int OFF_COL1 = 512;
constexpr int OFF_COR = 640;     // corners [b][hi][wi][16] -> 640..1151
constexpr int OFF_W1R = 1280;    // w1 A-frags hi(512 bf16)+lo(512 bf16) = 512 floats
constexpr int OFF_WR  = 2048;    // w2 A-frags hi(2560 bf16) + lo(2560 bf16)
constexpr int OFF_AFR = 8192;    // band A-frags: [b][10 frags][64 lanes] uint4 = 20480 floats
// ---- big buffers: tpl transposed [plane][b][j][h]; t0/t3 bf16, t1/t2 fp32 ----
constexpr size_t OFF_TP0 = 262144;                         // bytes
constexpr size_t SZ_TPH = (size_t)BN * PIX * 2;            // 4 MB (u16 plane)
constexpr size_t SZ_TPF = (size_t)BN * PIX * 4;            // 8 MB (f32 plane)
constexpr size_t OFF_TP1 = OFF_TP0 + SZ_TPH;
constexpr size_t OFF_TP2 = OFF_TP1 + SZ_TPF;
constexpr size_t OFF_TP3 = OFF_TP2 + SZ_TPF;
constexpr size_t WS_NEEDED = OFF_TP3 + SZ_TPH;             // ~25.4 MB

// ---------------- prep: zero atomic slots, swizzle w1/w2 into hi/lo A-fragments ----------------
__global__ void prep_kernel(const float* __restrict__ w1, const float* __restrict__ w2,
                            float* __restrict__ wsf) {
    int t = threadIdx.x;
    for (int i = t; i < 640; i += 256) wsf[i] = 0.f;
    unsigned short* ab = (unsigned short*)(wsf + OFF_WR);
    for (int idx = t; idx < 5120; idx += 256) {
        int part = idx / 2560;               // 0 = hi, 1 = lo
        int id = idx - part * 2560;
        int ks = id >> 9, rem = id & 511, lane = rem >> 3, j = id & 7;
        int oc = lane & 15, q = lane >> 4;
        int k = q * 8 + j;
        int tap = 2 * ks + (k >> 4), ic = k & 15;
        float val = (tap <= 8) ? w2[oc * 144 + ic * 9 + tap] : 0.f;
        float hv = b2f(f2b(val));
        ab[idx] = (part == 0) ? bfbits(val) : bfbits(val - hv);
    }
    unsigned short* a1 = (unsigned short*)(wsf + OFF_W1R);
    for (int idx = t; idx < 1024; idx += 256) {
        int part = idx >> 9;                 // 0 = hi, 1 = lo
        int id = idx & 511;
        int lane = id >> 3, j = id & 7;
        int oc = lane & 15, q = lane >> 4;
        int k = q * 8 + j;
        float val = (k < 27) ? w1[oc * 27 + k] : 0.f;
        float hv = b2f(f2b(val));
        a1[idx] = (part == 0) ? bfbits(val) : bfbits(val - hv);
    }
}

// ---------------- fused conv1(MFMA)+conv2(MFMA)+RGB with conv3-mean reduction ----------------
// (round-6 winner, unchanged)
__global__ __launch_bounds__(256) void conv12_kernel(const float* __restrict__ batch,
                                                     const unsigned short* __restrict__ w1buf,
                                                     const float* __restrict__ b1,
                                                     const unsigned short* __restrict__ abuf,
                                                     const float* __restrict__ b2v,
                                                     float* __restrict__ wsf,
                                                     float* __restrict__ out) {
    __shared__ unsigned short stb[3][12][68];
    __shared__ uint4 h1s[10 * 66 * 2];
    __shared__ float part[4][16];

    int tx = threadIdx.x;
    int lane = tx & 63, wave = tx >> 6;
    int n = lane & 15, q = lane >> 4;
    int w0 = blockIdx.x * 64, h0 = blockIdx.y * 8, b = blockIdx.z;

    union { uint4 u; bf16x8 v; } cv;
    const float* pb = batch + (size_t)(b * 3) * PIX;

    unsigned int* stw = (unsigned int*)&stb[0][0][0];
    for (int i = tx; i < 1224; i += 256) {
        int ch = i / 408, rem = i - ch * 408;
        int r = rem / 34, c2 = rem - r * 34;
        int gh = h0 - 2 + r, gw = w0 - 2 + 2 * c2;
        const float* p = pb + (size_t)ch * PIX + (size_t)gh * WW;
        bool rok = (gh >= 0) && (gh < HH);
        float v0 = (rok && gw >= 0 && gw < WW) ? p[gw] : 0.f;
        float v1 = (rok && gw + 1 >= 0 && gw + 1 < WW) ? p[gw + 1] : 0.f;
        stw[i] = cvtpk(v0, v1);
    }

    bf16x8 w1h, w1l;
    const uint4* w14 = (const uint4*)w1buf;
    cv.u = w14[lane];      w1h = cv.v;
    cv.u = w14[64 + lane]; w1l = cv.v;
    int koff[8];
#pragma unroll
    for (int j = 0; j < 8; j++) {
        int k = q * 8 + j;
        int kk = (k < 27) ? k : 0;
        int ic = kk / 9, rem = kk - ic * 9, kh = rem / 3, kw = rem - kh * 3;
        koff[j] = ic * 816 + kh * 68 + kw;
    }
    float b1q[4];
#pragma unroll
    for (int r = 0; r < 4; r++) b1q[r] = b1[q * 4 + r];
    bool hiq = (q == 3);
    __syncthreads();

    const unsigned short* sptr = &stb[0][0][0];
    unsigned int* hw = (unsigned int*)h1s;
    int i_c = wave * 16 + n;
    int r_c = (unsigned)i_c / 66u; int c_c = i_c - r_c * 66;
    int base_c = r_c * 68 + c_c;
    unsigned short x0 = sptr[base_c + koff[0]], x1 = sptr[base_c + koff[1]];
    unsigned short x2 = sptr[base_c + koff[2]], x3 = sptr[base_c + koff[3]];
    unsigned short x4 = sptr[base_c + koff[4]], x5 = sptr[base_c + koff[5]];
    unsigned short x6 = sptr[base_c + koff[6]], x7 = sptr[base_c + koff[7]];
    int g = wave;
    for (int gi = 0; gi < 11; gi++) {
        unsigned short y0 = 0, y1 = 0, y2 = 0, y3 = 0, y4 = 0, y5 = 0, y6 = 0, y7 = 0;
        int i_n = 0, c_n = 0;
        if (gi < 10) {
            i_n = (g + 4) * 16 + n; if (i_n > 659) i_n = 659;
            int r_n = (unsigned)i_n / 66u; c_n = i_n - r_n * 66;
            int base_n = r_n * 68 + c_n;
            y0 = sptr[base_n + koff[0]]; y1 = sptr[base_n + koff[1]];
            y2 = sptr[base_n + koff[2]]; y3 = sptr[base_n + koff[3]];
            y4 = sptr[base_n + koff[4]]; y5 = sptr[base_n + koff[5]];
            y6 = sptr[base_n + koff[6]]; y7 = sptr[base_n + koff[7]];
        }
        union { unsigned int w[4]; bf16x8 v; } bb;
        bb.w[0] = (unsigned int)x0 | ((unsigned int)x1 << 16);
        bb.w[1] = (unsigned int)x2 | ((unsigned int)x3 << 16);
        bb.w[2] = (unsigned int)x4 | ((unsigned int)x5 << 16);
        bb.w[3] = (unsigned int)x6 | ((unsigned int)x7 << 16);
        if (hiq) {
            bb.w[1] &= 0xFFFFu; bb.w[2] = 0u; bb.w[3] = 0u;
        }
        f32x4 a = {0, 0, 0, 0};
        MF(a, w1h, bb.v);
        MF(a, w1l, bb.v);
        int rr_ = (unsigned)i_c / 66u;
        int gh = h0 - 1 + rr_, gw = w0 - 1 + c_c;
        bool ok = ((unsigned)gh < (unsigned)HH) && ((unsigned)gw < (unsigned)WW);
        unsigned int p0 = cvtpk(silu(a[0] + b1q[0]), silu(a[1] + b1q[1]));
        unsigned int p1 = cvtpk(silu(a[2] + b1q[2]), silu(a[3] + b1q[3]));
        p0 = ok ? p0 : 0u;
        p1 = ok ? p1 : 0u;
        int swz = (c_c >> 2) & 1;
        int slot = i_c * 2 + ((q >= 2) ? (swz ^ 1) : swz);
        *(uint2*)&hw[slot * 4 + (q & 1) * 2] = make_uint2(p0, p1);
        x0 = y0; x1 = y1; x2 = y2; x3 = y3; x4 = y4; x5 = y5; x6 = y6; x7 = y7;
        i_c = i_n; c_c = c_n;
        g += 4;
    }

    for (int j = tx; j < 512; j += 256) {
        int rr = j >> 6, ccx = j & 63;
        size_t p = (size_t)(h0 + rr) * WW + (w0 + ccx);
        float v0 = pb[p], v1 = pb[(size_t)PIX + p], v2 = pb[2 * (size_t)PIX + p];
        int mx  = (v0 >= v1 && v0 >= v2) ? 0 : ((v1 >= v2) ? 1 : 2);
        int mx2 = (v2 >= v1 && v2 >= v0) ? 2 : ((v1 >= v0) ? 1 : 0);
        int mn  = (v0 <= v1 && v0 <= v2) ? 0 : ((v1 <= v2) ? 1 : 2);
        int mn2 = (v2 <= v1 && v2 <= v0) ? 2 : ((v1 <= v0) ? 1 : 0);
#pragma unroll
        for (int c = 0; c < 3; c++) {
            float r = 0.5f * ((float)(c == mx) + (float)(c == mx2))
                    - 0.5f * ((float)(c == mn) + (float)(c == mn2));
            out[(size_t)(b * 6 + 2 + c) * PIX + p] = r;
        }
    }
    __syncthreads();

    bf16x8 ah[5], al[5];
    const uint4* ab4 = (const uint4*)abuf;
#pragma unroll
    for (int ks = 0; ks < 5; ks++) {
        cv.u = ab4[ks * 64 + lane];       ah[ks] = cv.v;
        cv.u = ab4[320 + ks * 64 + lane]; al[ks] = cv.v;
    }
    float b2q[4];
#pragma unroll
    for (int r = 0; r < 4; r++) b2q[r] = b2v[q * 4 + r];

    float tt[4] = {0, 0, 0, 0};
    float cs0[4] = {0, 0, 0, 0};
    float cs1[4] = {0, 0, 0, 0};
    for (int rloc = 0; rloc < 2; rloc++) {
        int row = wave * 2 + rloc;
        int grow = h0 + row;
        f32x4 acc[4] = {{0,0,0,0},{0,0,0,0},{0,0,0,0},{0,0,0,0}};
#pragma unroll
        for (int ks = 0; ks < 5; ks++) {
            int tap = 2 * ks + (q >> 1); if (tap > 8) tap = 8;
            int dh = tap / 3 - 1, dw = tap % 3 - 1;
            int half = q & 1;
            int lr = row + 1 + dh;
#pragma unroll
            for (int t = 0; t < 4; t++) {
                int c = 1 + dw + t * 16 + n;
                cv.u = h1s[(lr * 66 + c) * 2 + (half ^ ((c >> 2) & 1))];
                MF(acc[t], ah[ks], cv.v);
                MF(acc[t], al[ks], cv.v);
            }
        }
        float sv[4][4];
#pragma unroll
        for (int t = 0; t < 4; t++)
#pragma unroll
            for (int r = 0; r < 4; r++)
                sv[t][r] = silu(acc[t][r] + b2q[r]);
#pragma unroll
        for (int r = 0; r < 4; r++) tt[r] += sv[0][r] + sv[1][r] + sv[2][r] + sv[3][r];
        if (grow == 0 || grow == HH - 1) {
            int off = (grow == 0) ? OFF_ROW0 : OFF_ROW1;
#pragma unroll
            for (int r = 0; r < 4; r++) {
                float x = sv[0][r] + sv[1][r] + sv[2][r] + sv[3][r];
#pragma unroll
                for (int d = 1; d < 16; d <<= 1) x += __shfl_xor(x, d, 64);
                if (n == 0) atomicAdd(&wsf[off + b * 16 + q * 4 + r], x);
            }
        }
        if (blockIdx.x == 0 && n == 0)
#pragma unroll
            for (int r = 0; r < 4; r++) cs0[r] += sv[0][r];
        if (blockIdx.x == 7 && n == 15)
#pragma unroll
            for (int r = 0; r < 4; r++) cs1[r] += sv[3][r];
        if ((grow == 0 || grow == HH - 1)) {
            int hi = (grow == 0) ? 0 : 1;
            if (blockIdx.x == 0 && n == 0)
#pragma unroll
                for (int r = 0; r < 4; r++)
                    wsf[OFF_COR + ((b * 2 + hi) * 2 + 0) * 16 + q * 4 + r] = sv[0][r];
            if (blockIdx.x == 7 && n == 15)
#pragma unroll
                for (int r = 0; r < 4; r++)
                    wsf[OFF_COR + ((b * 2 + hi) * 2 + 1) * 16 + q * 4 + r] = sv[3][r];
        }
    }
    if (blockIdx.x == 0 && n == 0)
#pragma unroll
        for (int r = 0; r < 4; r++) atomicAdd(&wsf[OFF_COL0 + b * 16 + q * 4 + r], cs0[r]);
    if (blockIdx.x == 7 && n == 15)
#pragma unroll
        for (int r = 0; r < 4; r++) atomicAdd(&wsf[OFF_COL1 + b * 16 + q * 4 + r], cs1[r]);
#pragma unroll
    for (int r = 0; r < 4; r++) {
        float x = tt[r];
#pragma unroll
        for (int d = 1; d < 16; d <<= 1) x += __shfl_xor(x, d, 64);
        tt[r] = x;
    }
    if (n == 0)
#pragma unroll
        for (int r = 0; r < 4; r++) part[wave][q * 4 + r] = tt[r];
    __syncthreads();
    if (tx < 16)
        atomicAdd(&wsf[OFF_TOT + b * 16 + tx],
                  part[0][tx] + part[1][tx] + part[2][tx] + part[3][tx]);
}

// ---------------- filter: mean via edge algebra, taps, and band-matrix A-fragments ----------------
__global__ void filter_kernel(const float* __restrict__ w3, const float* __restrict__ b3,
                              float* __restrict__ wsf) {
    int b = blockIdx.x, t = threadIdx.x;   // 160 threads
    __shared__ float red[160];
    float val = 0.f;
    if (t < 144) {
        int ic = t / 9, tap = t % 9, kh = tap / 3, kw = tap % 3;
        float T = wsf[OFF_TOT + b * 16 + ic];
        int hi = -1, wi = -1;
        if (kh == 0) { T -= wsf[OFF_ROW1 + b * 16 + ic]; hi = 1; }
        else if (kh == 2) { T -= wsf[OFF_ROW0 + b * 16 + ic]; hi = 0; }
        if (kw == 0) { T -= wsf[OFF_COL1 + b * 16 + ic]; wi = 1; }
        else if (kw == 2) { T -= wsf[OFF_COL0 + b * 16 + ic]; wi = 0; }
        if (hi >= 0 && wi >= 0) T += wsf[OFF_COR + ((b * 2 + hi) * 2 + wi) * 16 + ic];
        val = w3[t] * T;
    }
    red[t] = val;
    __syncthreads();
    __shared__ float sh_mean;
    if (t == 0) {
        float S = 0.f;
        for (int i = 0; i < 144; i++) S += red[i];
        sh_mean = b3[0] + S * (1.f / (float)PIX);
    }
    __syncthreads();
    float scale = fminf(2.5f, fmaxf(-2.5f, sh_mean));
    float sd = exp2f(scale);
    float fs = ceilf(3.f * sd + 0.5f);
    float e = 0.f, c = 0.f;
    if (t < 37) {
        float x = (float)(t - 18);
        if (fabsf(x) <= fs) {
            float qq = x / sd;
            e = __expf(-0.5f * qq * qq);
            c = -x / (sd * sd * sd * 6.28318530717958647692f) * e;
        }
    }
    __shared__ float sa[40], sb2[40];
    if (t < 37) { sa[t] = e; sb2[t] = fabsf(c); }
    __syncthreads();
    __shared__ float Se, Sc;
    if (t == 0) {
        float a = 0.f, d = 0.f;
        for (int i = 0; i < 37; i++) { a += sa[i]; d += sb2[i]; }
        Se = a; Sc = d;
    }
    __syncthreads();
    __shared__ float sEn[37], sCn[37];
    if (t < 37) { sEn[t] = e / Se; sCn[t] = c / Sc; }
    __syncthreads();
    if (t < 64) {
        int r = t & 15, q = t >> 4;
        uint4* afr = (uint4*)(wsf + OFF_AFR) + (size_t)b * 640 + t;
#pragma unroll
        for (int ks = 0; ks < 2; ks++) {
            unsigned short eh[8], em[8], el[8], chp[8], cmp[8];
#pragma unroll
            for (int j2 = 0; j2 < 8; j2++) {
                int d = ks * 32 + q * 8 + j2 - r;
                bool ok = (d >= 0) && (d <= 36);
                float ve = ok ? sEn[ok ? d : 0] : 0.f;
                float vc = ok ? sCn[ok ? d : 0] : 0.f;
                eh[j2] = bfbits(ve);
                float r1 = ve - ubf(eh[j2]);
                em[j2] = bfbits(r1);
                el[j2] = bfbits(r1 - ubf(em[j2]));
                chp[j2] = bfbits(vc);
                cmp[j2] = bfbits(vc - ubf(chp[j2]));
            }
#define PK2(a0, a1) ((unsigned)(a0) | ((unsigned)(a1) << 16))
            afr[(ks * 3 + 0) * 64] = make_uint4(PK2(eh[0], eh[1]), PK2(eh[2], eh[3]), PK2(eh[4], eh[5]), PK2(eh[6], eh[7]));
            afr[(ks * 3 + 1) * 64] = make_uint4(PK2(em[0], em[1]), PK2(em[2], em[3]), PK2(em[4], em[5]), PK2(em[6], em[7]));
            afr[(ks * 3 + 2) * 64] = make_uint4(PK2(el[0], el[1]), PK2(el[2], el[3]), PK2(el[4], el[5]), PK2(el[6], el[7]));
            afr[(6 + ks * 2 + 0) * 64] = make_uint4(PK2(chp[0], chp[1]), PK2(chp[2], chp[3]), PK2(chp[4], chp[5]), PK2(chp[6], chp[7]));
            afr[(6 + ks * 2 + 1) * 64] = make_uint4(PK2(cmp[0], cmp[1]), PK2(cmp[2], cmp[3]), PK2(cmp[4], cmp[5]), PK2(cmp[6], cmp[7]));
#undef PK2
        }
    }
}

// ---------------- horizontal pass (MFMA): batch -> xg -> t0..t3, tpl transposed [j][h] ----------------
// Batch-issued staging (T14): all 30 global loads hoisted into registers with one
// waitcnt, then converts+LDS writes.
__global__ __launch_bounds__(256) void horiz_kernel(const float* __restrict__ batch,
                                                    const float* __restrict__ gcm,
                                                    const float* __restrict__ wsf,
                                                    unsigned short* __restrict__ tp0,
                                                    float* __restrict__ tp1,
                                                    float* __restrict__ tp2,
                                                    unsigned short* __restrict__ tp3) {
    __shared__ unsigned short sx[7 * 32 * 84];   // 37,632 B
    int tx = threadIdx.x;
    int lane = tx & 63, wave = tx >> 6;
    int n = lane & 15, q = lane >> 4;
    int j0 = blockIdx.x * 32, h0 = blockIdx.y * 32, b = blockIdx.z;
    const float* pb = batch + (size_t)(b * 3) * PIX;
    float g0 = gcm[0], g1 = gcm[1], g2 = gcm[2];
    float g3 = gcm[3], g4 = gcm[4], g5 = gcm[5];
    float g6 = gcm[6], g7 = gcm[7], g8 = gcm[8];
    float v0r[10], v1r[10], v2r[10];
#pragma unroll
    for (int it = 0; it < 10; it++) {
        int i = tx + it * 256;                       // 0..2559
        int hh = i / 80, sc = i - hh * 80;
        int gc = j0 - 18 + sc;
        float v0 = 0.f, v1 = 0.f, v2 = 0.f;
        if ((unsigned)gc < (unsigned)WW) {
            size_t p = (size_t)(h0 + hh) * WW + gc;
            v0 = pb[p]; v1 = pb[(size_t)PIX + p]; v2 = pb[2 * (size_t)PIX + p];
        }
        v0r[it] = v0; v1r[it] = v1; v2r[it] = v2;
    }
#pragma unroll
    for (int it = 0; it < 10; it++) {
        int i = tx + it * 256;
        int hh = i / 80, sc = i - hh * 80;
        float v0 = v0r[it], v1 = v1r[it], v2 = v2r[it];
        float x0 = g0 * v0 + g1 * v1 + g2 * v2;
        float x1 = g3 * v0 + g4 * v1 + g5 * v2;
        float x2 = g6 * v0 + g7 * v1 + g8 * v2;
        int o = hh * 84 + sc;
        sx[o] = bfbits(x0);
        unsigned short h1 = bfbits(x1); sx[2688 + o] = h1;
        float r1 = x1 - ubf(h1); unsigned short m1 = bfbits(r1); sx[2 * 2688 + o] = m1;
        sx[3 * 2688 + o] = bfbits(r1 - ubf(m1));
        unsigned short h2 = bfbits(x2); sx[4 * 2688 + o] = h2;
        float r2 = x2 - ubf(h2); unsigned short m2 = bfbits(r2); sx[5 * 2688 + o] = m2;
        sx[6 * 2688 + o] = bfbits(r2 - ubf(m2));
    }
    const uint4* afr = (const uint4*)(wsf + OFF_AFR) + (size_t)b * 640 + lane;
    union { uint4 u; bf16x8 v; } cv;
    bf16x8 Ae[2][3], Ac[2][2];
#pragma unroll
    for (int ks = 0; ks < 2; ks++) {
#pragma unroll
        for (int p = 0; p < 3; p++) { cv.u = afr[(ks * 3 + p) * 64]; Ae[ks][p] = cv.v; }
#pragma unroll
        for (int p = 0; p < 2; p++) { cv.u = afr[(6 + ks * 2 + p) * 64]; Ac[ks][p] = cv.v; }
    }
    __syncthreads();
    int jt = wave & 1, ht = wave >> 1;
    f32x4 a0 = {0,0,0,0}, a1 = {0,0,0,0}, a2 = {0,0,0,0}, a3 = {0,0,0,0};
    int rb = (ht * 16 + n) * 84 + jt * 16 + q * 8;
#pragma unroll
    for (int ks = 0; ks < 2; ks++) {
        int rk = rb + ks * 32;
        bf16x8 B0  = ldb(sx, rk);
        bf16x8 B1h = ldb(sx, 2688 + rk), B1m = ldb(sx, 2 * 2688 + rk), B1l = ldb(sx, 3 * 2688 + rk);
        bf16x8 B2h = ldb(sx, 4 * 2688 + rk), B2m = ldb(sx, 5 * 2688 + rk), B2l = ldb(sx, 6 * 2688 + rk);
        MF(a0, Ae[ks][0], B0); MF(a0, Ae[ks][1], B0);
        MF(a3, Ac[ks][0], B0); MF(a3, Ac[ks][1], B0);
        MF(a1, Ae[ks][0], B1h); MF(a1, Ae[ks][0], B1m); MF(a1, Ae[ks][1], B1h);
        MF(a1, Ae[ks][0], B1l); MF(a1, Ae[ks][2], B1h); MF(a1, Ae[ks][1], B1m);
        MF(a2, Ae[ks][0], B2h); MF(a2, Ae[ks][0], B2m); MF(a2, Ae[ks][1], B2h);
        MF(a2, Ae[ks][0], B2l); MF(a2, Ae[ks][2], B2h); MF(a2, Ae[ks][1], B2m);
    }
    int jo = j0 + jt * 16 + q * 4;
    int ho = h0 + ht * 16 + n;
#pragma unroll
    for (int r = 0; r < 4; r++) {
        size_t ix = ((size_t)b * 512 + (jo + r)) * 512 + ho;
        tp0[ix] = bfbits(a0[r]);
        tp1[ix] = a1[r];
        tp2[ix] = a2[r];
        tp3[ix] = bfbits(a3[r]);
    }
}

// ---------------- vertical pass (MFMA) + final math -> out ch0,1,5 ----------------
// Batch-issued staging (T14), same pattern as horiz.
__global__ __launch_bounds__(256) void vert_kernel(const float* __restrict__ wsf,
                                                   const unsigned short* __restrict__ tp0,
                                                   const float* __restrict__ tp1,
                                                   const float* __restrict__ tp2,
                                                   const unsigned short* __restrict__ tp3,
                                                   float* __restrict__ out) {
    __shared__ unsigned short sb[8 * 32 * 84];   // 43,008 B
    int tx = threadIdx.x;
    int lane = tx & 63, wave = tx >> 6;
    int n = lane & 15, q = lane >> 4;
    int j0 = blockIdx.x * 32, r0 = blockIdx.y * 32, b = blockIdx.z;
    unsigned short w0r[10], w7r[10];
    float f1r[10], f2r[10];
#pragma unroll
    for (int it = 0; it < 10; it++) {
        int i = tx + it * 256;
        int jj = i / 80, sr = i - jj * 80;
        int gh = r0 - 18 + sr;
        unsigned short w0 = 0, w7 = 0; float f1 = 0.f, f2 = 0.f;
        if ((unsigned)gh < (unsigned)HH) {
            size_t ix = ((size_t)b * 512 + (j0 + jj)) * 512 + gh;
            w0 = tp0[ix]; f1 = tp1[ix]; f2 = tp2[ix]; w7 = tp3[ix];
        }
        w0r[it] = w0; f1r[it] = f1; f2r[it] = f2; w7r[it] = w7;
    }
#pragma unroll
    for (int it = 0; it < 10; it++) {
        int i = tx + it * 256;
        int jj = i / 80, sr = i - jj * 80;
        int o = jj * 84 + sr;
        float f1 = f1r[it], f2 = f2r[it];
        sb[o] = w0r[it];
        unsigned short h1 = bfbits(f1); sb[2688 + o] = h1;
        float r1 = f1 - ubf(h1); unsigned short m1 = bfbits(r1); sb[2 * 2688 + o] = m1;
        sb[3 * 2688 + o] = bfbits(r1 - ubf(m1));
        unsigned short h2 = bfbits(f2); sb[4 * 2688 + o] = h2;
        float r2 = f2 - ubf(h2); unsigned short m2 = bfbits(r2); sb[5 * 2688 + o] = m2;
        sb[6 * 2688 + o] = bfbits(r2 - ubf(m2));
        sb[7 * 2688 + o] = w7r[it];
    }
    const uint4* afr = (const uint4*)(wsf + OFF_AFR) + (size_t)b * 640 + lane;
    union { uint4 u; bf16x8 v; } cv;
    bf16x8 Ae[2][3], Ac[2][2];
#pragma unroll
    for (int ks = 0; ks < 2; ks++) {
#pragma unroll
        for (int p = 0; p < 3; p++) { cv.u = afr[(ks * 3 + p) * 64]; Ae[ks][p] = cv.v; }
#pragma unroll
        for (int p = 0; p < 2; p++) { cv.u = afr[(6 + ks * 2 + p) * 64]; Ac[ks][p] = cv.v; }
    }
    __syncthreads();
    int ct = wave & 1, rt = wave >> 1;
    f32x4 aE = {0,0,0,0}, aX = {0,0,0,0}, aY = {0,0,0,0}, aL = {0,0,0,0}, aLL = {0,0,0,0};
    int rb = (ct * 16 + n) * 84 + rt * 16 + q * 8;
#pragma unroll
    for (int ks = 0; ks < 2; ks++) {
        int rk = rb + ks * 32;
        bf16x8 B0  = ldb(sb, rk);
        bf16x8 B1h = ldb(sb, 2688 + rk), B1m = ldb(sb, 2 * 2688 + rk), B1l = ldb(sb, 3 * 2688 + rk);
        bf16x8 B2h = ldb(sb, 4 * 2688 + rk), B2m = ldb(sb, 5 * 2688 + rk), B2l = ldb(sb, 6 * 2688 + rk);
        bf16x8 B3  = ldb(sb, 7 * 2688 + rk);
        MF(aE, Ae[ks][0], B0); MF(aE, Ae[ks][1], B0);
        MF(aX, Ac[ks][0], B0); MF(aX, Ac[ks][1], B0);
        MF(aY, Ae[ks][0], B3); MF(aY, Ae[ks][1], B3);
        MF(aL, Ae[ks][0], B1h); MF(aL, Ae[ks][0], B1m); MF(aL, Ae[ks][1], B1h);
        MF(aL, Ae[ks][0], B1l); MF(aL, Ae[ks][2], B1h); MF(aL, Ae[ks][1], B1m);
        MF(aLL, Ae[ks][0], B2h); MF(aLL, Ae[ks][0], B2m); MF(aLL, Ae[ks][1], B2h);
        MF(aLL, Ae[ks][0], B2l); MF(aLL, Ae[ks][2], B2h); MF(aLL, Ae[ks][1], B2m);
    }
    int ho = r0 + rt * 16 + q * 4;
    int jo = j0 + ct * 16 + n;
#pragma unroll
    for (int r = 0; r < 4; r++) {
        float E = aE[r], Ex = aX[r], Ey = aY[r], El = aL[r], Ell = aLL[r];
        float Hf = atanf(El / (Ell + EPSF));
        float S = logf((El * El + Ell * Ell) / (E * E + EPSF) + EPSF);
        float rx = Ex / (E + EPSF), ry = Ey / (E + EPSF);
        float Wv = atanf(rx * rx + ry * ry);
        size_t base = (size_t)(b * 6) * PIX + (size_t)(ho + r) * WW + jo;
        out[base] = Hf;
        out[base + PIX] = S;
        out[base + 5 * (size_t)PIX] = Wv;
    }
}

extern "C" void kernel_launch(void* const* d_in, const int* in_sizes, int n_in,
                              void* d_out, int out_size, void* d_ws, size_t ws_size,
                              hipStream_t stream) {
    const float* batch = (const float*)d_in[0];
    const float* gcm   = (const float*)d_in[1];
    const float* w1    = (const float*)d_in[2];
    const float* b1    = (const float*)d_in[3];
    const float* w2    = (const float*)d_in[4];
    const float* b2    = (const float*)d_in[5];
    const float* w3    = (const float*)d_in[6];
    const float* b3    = (const float*)d_in[7];
    float* out = (float*)d_out;

    if (ws_size < WS_NEEDED) return;

    float* wsf = (float*)d_ws;
    unsigned short* tp0 = (unsigned short*)((char*)d_ws + OFF_TP0);
    float* tp1 = (float*)((char*)d_ws + OFF_TP1);
    float* tp2 = (float*)((char*)d_ws + OFF_TP2);
    unsigned short* tp3 = (unsigned short*)((char*)d_ws + OFF_TP3);

    prep_kernel<<<dim3(1), dim3(256), 0, stream>>>(w1, w2, wsf);
    conv12_kernel<<<dim3(8, 64, 8), dim3(256), 0, stream>>>(
        batch, (const unsigned short*)(wsf + OFF_W1R), b1,
        (const unsigned short*)(wsf + OFF_WR), b2, wsf, out);
    filter_kernel<<<dim3(8), dim3(160), 0, stream>>>(w3, b3, wsf);
    horiz_kernel<<<dim3(16, 16, 8), dim3(256), 0, stream>>>(batch, gcm, wsf, tp0, tp1, tp2, tp3);
    vert_kernel<<<dim3(16, 16, 8), dim3(256), 0, stream>>>(wsf, tp0, tp1, tp2, tp3, out);
}